// Round 3
// baseline (475.875 us; speedup 1.0000x reference)
//
#include <hip/hip_runtime.h>
#include <hip/hip_bf16.h>
#include <math.h>
#include <stdint.h>

// Problem constants
#define BATCH 8
#define SEQ   2048
#define DMODEL 1024
#define GROUPS 2
#define VOCAB 320
#define NOUT  (GROUPS*VOCAB)   // 640
#define DG    (DMODEL/GROUPS)  // 512
#define NTOK  (BATCH*SEQ)      // 16384
#define NPAIR (NTOK*GROUPS)    // 32768

#define MARGIN 3.0f
#define NEG_INF (-3.0e38f)

typedef __attribute__((ext_vector_type(8))) short short8;
typedef __attribute__((ext_vector_type(8))) unsigned short ushort8;
typedef __attribute__((ext_vector_type(4))) float f32x4;

__device__ __forceinline__ unsigned short f2bf(float f) {
    __hip_bfloat16 h = __float2bfloat16(f);   // RNE
    return *reinterpret_cast<unsigned short*>(&h);
}
__device__ __forceinline__ float bf2f(unsigned short u) {
    unsigned int x = ((unsigned int)u) << 16;
    return __uint_as_float(x);
}

// async global->LDS 16B copy (wave-uniform base + lane*16 on the LDS side)
__device__ __forceinline__ void async16(const void* gptr, const void* lptr) {
    __builtin_amdgcn_global_load_lds(
        (const __attribute__((address_space(1))) unsigned int*)(unsigned long long)(uintptr_t)gptr,
        (__attribute__((address_space(3))) unsigned int*)(unsigned int)(uintptr_t)lptr,
        16, 0, 0);
}

// ---------------------------------------------------------------------------
// Kernel 1: fp32 -> bf16 conversion of X and W   (unchanged, proven)
// ---------------------------------------------------------------------------
#define NX4 (NTOK*DMODEL/4)    // 4194304
#define NW4 (NOUT*DMODEL/4)    // 163840
__global__ __launch_bounds__(256) void convert_kernel(
    const float* __restrict__ X, const float* __restrict__ W,
    unsigned short* __restrict__ Xb, unsigned short* __restrict__ Wb)
{
    int i = blockIdx.x * 256 + threadIdx.x;
    const float4* src;
    ushort4* dst;
    int j;
    if (i < NX4) { src = (const float4*)X; dst = (ushort4*)Xb; j = i; }
    else         { src = (const float4*)W; dst = (ushort4*)Wb; j = i - NX4; if (j >= NW4) return; }
    float4 v = src[j];
    ushort4 u;
    u.x = f2bf(v.x); u.y = f2bf(v.y); u.z = f2bf(v.z); u.w = f2bf(v.w);
    dst[j] = u;
}

// ---------------------------------------------------------------------------
// Kernel 2: bf16 MFMA GEMM  logits[16384][640] (bf16) = Xb @ Wb^T + bias
// (unchanged, proven in round 2)
// ---------------------------------------------------------------------------
__global__ __launch_bounds__(256) void gemm_bf16_kernel(
    const unsigned short* __restrict__ Xb,   // [16384][1024]
    const unsigned short* __restrict__ Wb,   // [640][1024]
    const float* __restrict__ bias,          // [640]
    unsigned short* __restrict__ logits)     // [16384][640] bf16
{
    __shared__ __align__(16) unsigned short As[128 * 32];  // 8 KB
    __shared__ __align__(16) unsigned short Bs[128 * 32];  // 8 KB

    const int tid  = threadIdx.x;
    const int lane = tid & 63;
    const int wave = tid >> 6;
    const int m0 = blockIdx.x * 128;
    const int n0 = blockIdx.y * 128;
    const int wm = (wave & 1) * 64;
    const int wn = (wave >> 1) * 64;

    f32x4 acc[4][4];
    #pragma unroll
    for (int a = 0; a < 4; a++)
        #pragma unroll
        for (int b = 0; b < 4; b++)
            acc[a][b] = (f32x4)0.0f;

    int aoff[2], boff[2], loff[2];
    #pragma unroll
    for (int j = 0; j < 2; j++) {
        int p = tid + j * 256;
        int r = p >> 2, s = p & 3;
        int c = s ^ ((r >> 1) & 3);
        aoff[j] = (m0 + r) * DMODEL + c * 8;
        boff[j] = (n0 + r) * DMODEL + c * 8;
        loff[j] = p * 8;
    }

    int afrag[4], bfrag[4];
    {
        int rho = lane & 15, h = lane >> 4;
        #pragma unroll
        for (int mi = 0; mi < 4; mi++) {
            int r = wm + mi * 16 + rho;
            afrag[mi] = (4 * r + (h ^ ((r >> 1) & 3))) * 8;
            int rn = wn + mi * 16 + rho;
            bfrag[mi] = (4 * rn + (h ^ ((rn >> 1) & 3))) * 8;
        }
    }

    for (int k0 = 0; k0 < DMODEL; k0 += 32) {
        #pragma unroll
        for (int j = 0; j < 2; j++) {
            async16(Xb + aoff[j] + k0, As + loff[j]);
            async16(Wb + boff[j] + k0, Bs + loff[j]);
        }
        __syncthreads();

        short8 af[4], bf[4];
        #pragma unroll
        for (int i = 0; i < 4; i++) {
            af[i] = *(const short8*)&As[afrag[i]];
            bf[i] = *(const short8*)&Bs[bfrag[i]];
        }
        #pragma unroll
        for (int mi = 0; mi < 4; mi++)
            #pragma unroll
            for (int ni = 0; ni < 4; ni++)
                acc[mi][ni] = __builtin_amdgcn_mfma_f32_16x16x32_bf16(
                    af[mi], bf[ni], acc[mi][ni], 0, 0, 0);
        __syncthreads();
    }

    const int colb = n0 + wn + (lane & 15);
    const int rowb = m0 + wm + (lane >> 4) * 4;
    float bv[4];
    #pragma unroll
    for (int ni = 0; ni < 4; ni++) bv[ni] = bias[colb + ni * 16];
    #pragma unroll
    for (int mi = 0; mi < 4; mi++)
        #pragma unroll
        for (int ni = 0; ni < 4; ni++)
            #pragma unroll
            for (int p = 0; p < 4; p++) {
                int row = rowb + mi * 16 + p;
                int col = colb + ni * 16;
                logits[row * NOUT + col] = f2bf(acc[mi][ni][p] + bv[ni]);
            }
}

// ---------------------------------------------------------------------------
// Kernel 3 (merged select): one wave per (token,group) pair.
//   - 40 lanes load 8 bf16 logits each (one 16B load)
//   - butterfly approx-argmax; margin test
//   - ambiguous: candidate lanes run exact fp32 ascending-fmaf chains in
//     SIMD lockstep (no atomics, no lists)
//   - lane 0 writes idx + one histogram atomic (640 spread bins)
//   - wave gathers winning codevector row (64 lanes x 2 float4)
// ---------------------------------------------------------------------------
__global__ __launch_bounds__(256) void select_kernel(
    const unsigned short* __restrict__ logits,
    const float* __restrict__ X, const float* __restrict__ W,
    const float* __restrict__ bias, const float* __restrict__ cb,
    float* __restrict__ out, float* __restrict__ out_idx,
    int* __restrict__ hist)
{
    const int wave = threadIdx.x >> 6;
    const int lane = threadIdx.x & 63;
    const int pair = blockIdx.x * 4 + wave;
    const int token = pair >> 1;
    const int g = pair & 1;

    const unsigned short* lp = logits + token * NOUT + g * VOCAB;

    // 40 lanes x 8 bf16 = 320 logits
    float v[8];
    const bool have = (lane < 40);
    if (have) {
        ushort8 u = *(const ushort8*)(lp + lane * 8);
        #pragma unroll
        for (int j = 0; j < 8; j++) v[j] = bf2f(u[j]);
    } else {
        #pragma unroll
        for (int j = 0; j < 8; j++) v[j] = NEG_INF;
    }

    // approx argmax (first occurrence)
    float best = NEG_INF;
    int bi = 0x7FFFFFFF;
    if (have) {
        best = v[0]; bi = lane * 8;
        #pragma unroll
        for (int j = 1; j < 8; j++)
            if (v[j] > best) { best = v[j]; bi = lane * 8 + j; }
    }
    #pragma unroll
    for (int off = 32; off > 0; off >>= 1) {
        float ov = __shfl_xor(best, off);
        int   oi = __shfl_xor(bi, off);
        if (ov > best || (ov == best && oi < bi)) { best = ov; bi = oi; }
    }

    // margin candidates
    const float thr = best - MARGIN;
    int cnt = 0;
    if (have) {
        #pragma unroll
        for (int j = 0; j < 8; j++) cnt += (v[j] >= thr) ? 1 : 0;
    }
    int tot = cnt;
    #pragma unroll
    for (int off = 32; off > 0; off >>= 1) tot += __shfl_xor(tot, off);

    int win;
    if (tot == 1) {
        win = bi;   // unique candidate == approx argmax; wave-uniform after butterfly
    } else {
        // exact fp32 rescore, candidate lanes in SIMD lockstep
        float ebest = NEG_INF;
        int eidx = 0x7FFFFFFF;
        if (have && cnt > 0) {
            const float4* xr = (const float4*)(X + (size_t)token * DMODEL);
            #pragma unroll
            for (int j = 0; j < 8; j++) {
                if (v[j] >= thr) {
                    const int col = lane * 8 + j;
                    const float4* wr = (const float4*)(W + (size_t)(g * VOCAB + col) * DMODEL);
                    float acc = 0.0f;
                    #pragma unroll 4
                    for (int k = 0; k < DMODEL / 4; k++) {
                        float4 a = xr[k], b = wr[k];
                        acc = fmaf(a.x, b.x, acc);
                        acc = fmaf(a.y, b.y, acc);
                        acc = fmaf(a.z, b.z, acc);
                        acc = fmaf(a.w, b.w, acc);
                    }
                    float logit = acc + bias[g * VOCAB + col];
                    if (logit > ebest || (logit == ebest && col < eidx)) {
                        ebest = logit; eidx = col;
                    }
                }
            }
        }
        #pragma unroll
        for (int off = 32; off > 0; off >>= 1) {
            float ov = __shfl_xor(ebest, off);
            int   oi = __shfl_xor(eidx, off);
            if (ov > ebest || (ov == ebest && oi < eidx)) { ebest = ov; eidx = oi; }
        }
        win = eidx;
    }

    if (lane == 0) {
        out_idx[pair] = (float)win;
        atomicAdd(&hist[g * VOCAB + win], 1);
    }

    // gather winning codevector: 512 floats = 128 float4, 2 per lane
    const float4* src = (const float4*)(cb + (size_t)(g * VOCAB + win) * DG);
    float4* dst = (float4*)(out + (size_t)token * DMODEL + g * DG);
    dst[lane]      = src[lane];
    dst[lane + 64] = src[lane + 64];
}

// ---------------------------------------------------------------------------
// Kernel 4: diversity loss scalar
// ---------------------------------------------------------------------------
__global__ __launch_bounds__(256) void diversity_kernel(
    const int* __restrict__ hist, float* __restrict__ out_scalar)
{
    __shared__ float s0[256], s1[256];
    const int tid = threadIdx.x;
    float a0 = 0.0f, a1 = 0.0f;
    for (int i = tid; i < NOUT; i += 256) {
        float m = (float)hist[i] * (1.0f / (float)NTOK);
        float t = m * logf(m + 1e-7f);
        if (i < VOCAB) a0 += t; else a1 += t;
    }
    s0[tid] = a0; s1[tid] = a1;
    __syncthreads();
    for (int s = 128; s > 0; s >>= 1) {
        if (tid < s) { s0[tid] += s0[tid + s]; s1[tid] += s1[tid + s]; }
        __syncthreads();
    }
    if (tid == 0) {
        float perplexity = expf(-s0[0]) + expf(-s1[0]);
        *out_scalar = ((float)NOUT - perplexity) / (float)NOUT * 0.1f;
    }
}

// ---------------------------------------------------------------------------
extern "C" void kernel_launch(void* const* d_in, const int* in_sizes, int n_in,
                              void* d_out, int out_size, void* d_ws, size_t ws_size,
                              hipStream_t stream) {
    const float* X    = (const float*)d_in[0];  // [8,2048,1024]
    const float* W    = (const float*)d_in[1];  // [640,1024]
    const float* bias = (const float*)d_in[2];  // [640]
    const float* cb   = (const float*)d_in[3];  // [1,640,512]

    float* out      = (float*)d_out;                   // [16384*1024]
    float* out_idx  = out + (size_t)NTOK * DMODEL;     // [32768]
    float* out_loss = out_idx + NPAIR;                 // [1]

    // workspace layout
    char* p = (char*)d_ws;
    unsigned short* Xb = (unsigned short*)p;      p += (size_t)NTOK * DMODEL * 2;  // 32 MB
    unsigned short* Wb = (unsigned short*)p;      p += (size_t)NOUT * DMODEL * 2;  // 1.25 MB
    unsigned short* logits = (unsigned short*)p;  p += (size_t)NTOK * NOUT * 2;    // 20 MB
    int* hist = (int*)p;                          p += NOUT * 4;

    hipMemsetAsync(hist, 0, NOUT * sizeof(int), stream);

    convert_kernel<<<(NX4 + NW4) / 256, 256, 0, stream>>>(X, W, Xb, Wb);

    dim3 ggrid(NTOK / 128, NOUT / 128);  // 128 x 5
    gemm_bf16_kernel<<<ggrid, 256, 0, stream>>>(Xb, Wb, bias, logits);

    select_kernel<<<NPAIR / 4, 256, 0, stream>>>(
        logits, X, W, bias, cb, out, out_idx, hist);

    diversity_kernel<<<1, 256, 0, stream>>>(hist, out_loss);
}

// Round 4
// 290.198 us; speedup vs baseline: 1.6398x; 1.6398x over previous
//
#include <hip/hip_runtime.h>
#include <hip/hip_bf16.h>
#include <math.h>
#include <stdint.h>

// Problem constants
#define BATCH 8
#define SEQ   2048
#define DMODEL 1024
#define GROUPS 2
#define VOCAB 320
#define NOUT  (GROUPS*VOCAB)   // 640
#define DG    (DMODEL/GROUPS)  // 512
#define NTOK  (BATCH*SEQ)      // 16384
#define NPAIR (NTOK*GROUPS)    // 32768
#define NCHUNK 10              // 64-col chunks per token

#define MARGIN 4.0f
#define NEG_INF (-3.0e38f)
#define MAXCAND 32

typedef __attribute__((ext_vector_type(8))) short short8;
typedef __attribute__((ext_vector_type(8))) unsigned short ushort8;
typedef __attribute__((ext_vector_type(4))) float f32x4;

__device__ __forceinline__ unsigned short f2bf(float f) {
    __hip_bfloat16 h = __float2bfloat16(f);   // RNE
    return *reinterpret_cast<unsigned short*>(&h);
}
__device__ __forceinline__ float bf2f(unsigned short u) {
    unsigned int x = ((unsigned int)u) << 16;
    return __uint_as_float(x);
}

// async global->LDS 16B copy (wave-uniform base + lane*16 on the LDS side)
__device__ __forceinline__ void async16(const void* gptr, const void* lptr) {
    __builtin_amdgcn_global_load_lds(
        (const __attribute__((address_space(1))) unsigned int*)(unsigned long long)(uintptr_t)gptr,
        (__attribute__((address_space(3))) unsigned int*)(unsigned int)(uintptr_t)lptr,
        16, 0, 0);
}

// ---------------------------------------------------------------------------
// Kernel 1: fp32 -> bf16 conversion of X and W   (proven)
// ---------------------------------------------------------------------------
#define NX4 (NTOK*DMODEL/4)    // 4194304
#define NW4 (NOUT*DMODEL/4)    // 163840
__global__ __launch_bounds__(256) void convert_kernel(
    const float* __restrict__ X, const float* __restrict__ W,
    unsigned short* __restrict__ Xb, unsigned short* __restrict__ Wb)
{
    int i = blockIdx.x * 256 + threadIdx.x;
    const float4* src;
    ushort4* dst;
    int j;
    if (i < NX4) { src = (const float4*)X; dst = (ushort4*)Xb; j = i; }
    else         { src = (const float4*)W; dst = (ushort4*)Wb; j = i - NX4; if (j >= NW4) return; }
    float4 v = src[j];
    ushort4 u;
    u.x = f2bf(v.x); u.y = f2bf(v.y); u.z = f2bf(v.z); u.w = f2bf(v.w);
    dst[j] = u;
}

// ---------------------------------------------------------------------------
// Kernel 2: bf16 MFMA GEMM + fused per-(token,chunk) (max1,max2,argmax)
// records from fp32 accumulators; also stores bf16 logits.
// ---------------------------------------------------------------------------
__global__ __launch_bounds__(256) void gemm_bf16_kernel(
    const unsigned short* __restrict__ Xb,   // [16384][1024]
    const unsigned short* __restrict__ Wb,   // [640][1024]
    const float* __restrict__ bias,          // [640]
    unsigned short* __restrict__ logits,     // [16384][640] bf16
    float* __restrict__ rec_m1,              // [NTOK][NCHUNK]
    float* __restrict__ rec_m2,              // [NTOK][NCHUNK]
    int*   __restrict__ rec_id)              // [NTOK][NCHUNK] (global col)
{
    __shared__ __align__(16) unsigned short As[128 * 32];  // 8 KB
    __shared__ __align__(16) unsigned short Bs[128 * 32];  // 8 KB

    const int tid  = threadIdx.x;
    const int lane = tid & 63;
    const int wave = tid >> 6;
    const int m0 = blockIdx.x * 128;
    const int n0 = blockIdx.y * 128;
    const int wm = (wave & 1) * 64;
    const int wn = (wave >> 1) * 64;

    f32x4 acc[4][4];
    #pragma unroll
    for (int a = 0; a < 4; a++)
        #pragma unroll
        for (int b = 0; b < 4; b++)
            acc[a][b] = (f32x4)0.0f;

    int aoff[2], boff[2], loff[2];
    #pragma unroll
    for (int j = 0; j < 2; j++) {
        int p = tid + j * 256;
        int r = p >> 2, s = p & 3;
        int c = s ^ ((r >> 1) & 3);
        aoff[j] = (m0 + r) * DMODEL + c * 8;
        boff[j] = (n0 + r) * DMODEL + c * 8;
        loff[j] = p * 8;
    }

    int afrag[4], bfrag[4];
    {
        int rho = lane & 15, h = lane >> 4;
        #pragma unroll
        for (int mi = 0; mi < 4; mi++) {
            int r = wm + mi * 16 + rho;
            afrag[mi] = (4 * r + (h ^ ((r >> 1) & 3))) * 8;
            int rn = wn + mi * 16 + rho;
            bfrag[mi] = (4 * rn + (h ^ ((rn >> 1) & 3))) * 8;
        }
    }

    for (int k0 = 0; k0 < DMODEL; k0 += 32) {
        #pragma unroll
        for (int j = 0; j < 2; j++) {
            async16(Xb + aoff[j] + k0, As + loff[j]);
            async16(Wb + boff[j] + k0, Bs + loff[j]);
        }
        __syncthreads();

        short8 af[4], bf[4];
        #pragma unroll
        for (int i = 0; i < 4; i++) {
            af[i] = *(const short8*)&As[afrag[i]];
            bf[i] = *(const short8*)&Bs[bfrag[i]];
        }
        #pragma unroll
        for (int mi = 0; mi < 4; mi++)
            #pragma unroll
            for (int ni = 0; ni < 4; ni++)
                acc[mi][ni] = __builtin_amdgcn_mfma_f32_16x16x32_bf16(
                    af[mi], bf[ni], acc[mi][ni], 0, 0, 0);
        __syncthreads();
    }

    // Epilogue: bias add, bf16 logit store, per-row (64-col) max1/max2/idx
    const int colb = n0 + wn + (lane & 15);
    const int rowb = m0 + wm + (lane >> 4) * 4;
    const int chunk = (n0 + wn) >> 6;   // 0..9
    float bv[4];
    #pragma unroll
    for (int ni = 0; ni < 4; ni++) bv[ni] = bias[colb + ni * 16];

    #pragma unroll
    for (int mi = 0; mi < 4; mi++) {
        #pragma unroll
        for (int p = 0; p < 4; p++) {
            const int row = rowb + mi * 16 + p;
            // local max over this lane's 4 cols (ascending col order)
            float m1 = acc[mi][0][p] + bv[0];
            float m2 = NEG_INF;
            int i1 = colb;
            logits[row * NOUT + colb] = f2bf(m1);
            #pragma unroll
            for (int ni = 1; ni < 4; ni++) {
                float v = acc[mi][ni][p] + bv[ni];
                logits[row * NOUT + colb + ni * 16] = f2bf(v);
                if (v > m1) { m2 = m1; m1 = v; i1 = colb + ni * 16; }
                else        { m2 = fmaxf(m2, v); }
            }
            // reduce across the 16 lanes of this row group (xor 1,2,4,8)
            #pragma unroll
            for (int off = 1; off < 16; off <<= 1) {
                float om1 = __shfl_xor(m1, off);
                float om2 = __shfl_xor(m2, off);
                int   oi  = __shfl_xor(i1, off);
                float nm2 = fmaxf(fmaxf(m2, om2), fminf(m1, om1));
                if (om1 > m1 || (om1 == m1 && oi < i1)) { m1 = om1; i1 = oi; }
                m2 = nm2;
            }
            if ((lane & 15) == 0) {
                rec_m1[row * NCHUNK + chunk] = m1;
                rec_m2[row * NCHUNK + chunk] = m2;
                rec_id[row * NCHUNK + chunk] = i1;
            }
        }
    }
}

// ---------------------------------------------------------------------------
// Kernel 3: dense reduce, thread-per-pair. Unique -> idx; ambiguous ->
// append (M, pair) to list via wave-aggregated atomic.
// ---------------------------------------------------------------------------
__global__ __launch_bounds__(256) void reduce_kernel(
    const float* __restrict__ rec_m1, const float* __restrict__ rec_m2,
    const int* __restrict__ rec_id,
    float* __restrict__ out_idx,
    unsigned long long* __restrict__ list, int* __restrict__ nAmb)
{
    const int pair = blockIdx.x * 256 + threadIdx.x;   // 32768 threads
    const int token = pair >> 1;
    const int g = pair & 1;
    const int base = token * NCHUNK + g * 5;

    float m1[5], m2s, M;
    int cstar = 0;
    #pragma unroll
    for (int c = 0; c < 5; c++) m1[c] = rec_m1[base + c];
    M = m1[0];
    #pragma unroll
    for (int c = 1; c < 5; c++)
        if (m1[c] > M) { M = m1[c]; cstar = c; }
    m2s = rec_m2[base + cstar];

    const float thr = M - MARGIN;
    bool amb = (m2s >= thr);
    #pragma unroll
    for (int c = 0; c < 5; c++)
        if (c != cstar && m1[c] >= thr) amb = true;

    if (!amb) {
        out_idx[pair] = (float)(rec_id[base + cstar] - g * VOCAB);
    } else {
        out_idx[pair] = -1.0f;
    }

    // wave-aggregated append
    unsigned long long mask = __ballot(amb);
    if (mask) {
        const int lane = threadIdx.x & 63;
        const int leader = __ffsll((long long)mask) - 1;
        int basepos = 0;
        if (lane == leader) basepos = atomicAdd(nAmb, (int)__popcll(mask));
        basepos = __shfl(basepos, leader);
        if (amb) {
            int off = __popcll(mask & ((1ull << lane) - 1ull));
            list[basepos + off] =
                ((unsigned long long)__float_as_uint(M) << 32) | (unsigned int)pair;
        }
    }
}

// ---------------------------------------------------------------------------
// Kernel 4: extract candidates for ambiguous pairs (wave-per-slot, no atomics)
// ---------------------------------------------------------------------------
__global__ __launch_bounds__(256) void extract_kernel(
    const unsigned short* __restrict__ logits,
    const unsigned long long* __restrict__ list, const int* __restrict__ nAmb,
    unsigned short* __restrict__ cand,   // [NPAIR][MAXCAND] within-group cols
    int* __restrict__ cnt)               // [NPAIR slots]
{
    const int wave = threadIdx.x >> 6;
    const int lane = threadIdx.x & 63;
    const int slot = blockIdx.x * 4 + wave;
    if (slot >= *nAmb) return;

    unsigned long long e = list[slot];
    const int pair = (int)(e & 0xFFFFFFFFull);
    const float M = __uint_as_float((unsigned int)(e >> 32));
    const int token = pair >> 1;
    const int g = pair & 1;

    const unsigned short* lp = logits + token * NOUT + g * VOCAB;
    const bool have = (lane < 40);
    float v[8];
    if (have) {
        ushort8 u = *(const ushort8*)(lp + lane * 8);
        #pragma unroll
        for (int j = 0; j < 8; j++) v[j] = bf2f(u[j]);
    } else {
        #pragma unroll
        for (int j = 0; j < 8; j++) v[j] = NEG_INF;
    }

    const float thr = M - MARGIN;
    unsigned short* cd = cand + (size_t)slot * MAXCAND;
    int total = 0;
    #pragma unroll
    for (int j = 0; j < 8; j++) {
        bool c = have && (v[j] >= thr);
        unsigned long long mask = __ballot(c);
        if (c) {
            int pos = total + __popcll(mask & ((1ull << lane) - 1ull));
            if (pos < MAXCAND) cd[pos] = (unsigned short)(lane * 8 + j);
        }
        total += (int)__popcll(mask);
    }
    if (lane == 0) cnt[slot] = (total < MAXCAND) ? total : MAXCAND;
}

// ---------------------------------------------------------------------------
// Kernel 5: dense exact rescore, thread-per-candidate (proven-exact chain)
// ---------------------------------------------------------------------------
__global__ __launch_bounds__(256) void rescore_kernel(
    const float* __restrict__ X, const float* __restrict__ W,
    const float* __restrict__ bias,
    const unsigned long long* __restrict__ list, const int* __restrict__ nAmb,
    const unsigned short* __restrict__ cand, const int* __restrict__ cnt,
    unsigned long long* __restrict__ keys)   // [NPAIR]
{
    const int gid = blockIdx.x * 256 + threadIdx.x;
    const int slot = gid >> 5;          // MAXCAND = 32
    const int c = gid & 31;
    if (slot >= *nAmb) return;
    if (c >= cnt[slot]) return;

    const int pair = (int)(list[slot] & 0xFFFFFFFFull);
    const int token = pair >> 1;
    const int g = pair & 1;
    const int col = (int)cand[(size_t)slot * MAXCAND + c];   // 0..319

    const float4* xr = (const float4*)(X + (size_t)token * DMODEL);
    const float4* wr = (const float4*)(W + (size_t)(g * VOCAB + col) * DMODEL);
    float acc = 0.0f;
    #pragma unroll 4
    for (int k = 0; k < DMODEL / 4; k++) {
        float4 a = xr[k], b = wr[k];
        acc = fmaf(a.x, b.x, acc);
        acc = fmaf(a.y, b.y, acc);
        acc = fmaf(a.z, b.z, acc);
        acc = fmaf(a.w, b.w, acc);
    }
    float logit = acc + bias[g * VOCAB + col];

    unsigned int ub = __float_as_uint(logit);
    unsigned int key32 = (ub & 0x80000000u) ? ~ub : (ub | 0x80000000u);
    unsigned long long key = ((unsigned long long)key32 << 32)
                           | (unsigned int)(511 - col);   // smaller col wins ties
    atomicMax(&keys[pair], key);
}

// ---------------------------------------------------------------------------
// Kernel 6: block-cooperative finalize + gather (16 tokens / block)
// ---------------------------------------------------------------------------
__global__ __launch_bounds__(256) void gather_kernel(
    const float* __restrict__ cb,
    const unsigned long long* __restrict__ keys,
    float* __restrict__ out, float* __restrict__ out_idx,
    int* __restrict__ hist)
{
    __shared__ int gidx[32];
    const int t0 = blockIdx.x * 16;     // first token
    const int tid = threadIdx.x;

    if (tid < 32) {
        const int pair = t0 * 2 + tid;
        const int g = pair & 1;
        float f = out_idx[pair];
        int col;
        if (f < -0.5f) {
            unsigned long long k = keys[pair];
            col = 511 - (int)(k & 0xFFFFFFFFull);
            out_idx[pair] = (float)col;
        } else {
            col = (int)f;
        }
        gidx[tid] = g * VOCAB + col;
        atomicAdd(&hist[g * VOCAB + col], 1);
    }
    __syncthreads();

    // copy 16 tokens x 1024 floats; per iter: 256 float4 = one token row
    const int g = tid >> 7;          // 0..1
    const int off4 = tid & 127;      // float4 within the 512-float half
    #pragma unroll 4
    for (int i = 0; i < 16; i++) {
        const int token = t0 + i;
        const float4* src = (const float4*)(cb + (size_t)gidx[i * 2 + g] * DG);
        ((float4*)(out + (size_t)token * DMODEL))[tid] = src[off4];
    }
}

// ---------------------------------------------------------------------------
// Kernel 7: diversity loss scalar
// ---------------------------------------------------------------------------
__global__ __launch_bounds__(256) void diversity_kernel(
    const int* __restrict__ hist, float* __restrict__ out_scalar)
{
    __shared__ float s0[256], s1[256];
    const int tid = threadIdx.x;
    float a0 = 0.0f, a1 = 0.0f;
    for (int i = tid; i < NOUT; i += 256) {
        float m = (float)hist[i] * (1.0f / (float)NTOK);
        float t = m * logf(m + 1e-7f);
        if (i < VOCAB) a0 += t; else a1 += t;
    }
    s0[tid] = a0; s1[tid] = a1;
    __syncthreads();
    for (int s = 128; s > 0; s >>= 1) {
        if (tid < s) { s0[tid] += s0[tid + s]; s1[tid] += s1[tid + s]; }
        __syncthreads();
    }
    if (tid == 0) {
        float perplexity = expf(-s0[0]) + expf(-s1[0]);
        *out_scalar = ((float)NOUT - perplexity) / (float)NOUT * 0.1f;
    }
}

// ---------------------------------------------------------------------------
extern "C" void kernel_launch(void* const* d_in, const int* in_sizes, int n_in,
                              void* d_out, int out_size, void* d_ws, size_t ws_size,
                              hipStream_t stream) {
    const float* X    = (const float*)d_in[0];
    const float* W    = (const float*)d_in[1];
    const float* bias = (const float*)d_in[2];
    const float* cb   = (const float*)d_in[3];

    float* out      = (float*)d_out;
    float* out_idx  = out + (size_t)NTOK * DMODEL;
    float* out_loss = out_idx + NPAIR;

    // workspace layout
    char* p = (char*)d_ws;
    unsigned short* Xb = (unsigned short*)p;      p += (size_t)NTOK * DMODEL * 2;   // 32 MB
    unsigned short* Wb = (unsigned short*)p;      p += (size_t)NOUT * DMODEL * 2;   // 1.25 MB
    unsigned short* logits = (unsigned short*)p;  p += (size_t)NTOK * NOUT * 2;     // 20 MB
    float* rec_m1 = (float*)p;                    p += (size_t)NTOK * NCHUNK * 4;   // 640 KB
    float* rec_m2 = (float*)p;                    p += (size_t)NTOK * NCHUNK * 4;
    int*   rec_id = (int*)p;                      p += (size_t)NTOK * NCHUNK * 4;
    unsigned long long* list = (unsigned long long*)p; p += (size_t)NPAIR * 8;      // 256 KB
    unsigned short* cand = (unsigned short*)p;    p += (size_t)NPAIR * MAXCAND * 2; // 2 MB
    int* cnt = (int*)p;                           p += (size_t)NPAIR * 4;           // 128 KB
    // zeroed region: keys | nAmb(+pad) | hist
    unsigned long long* keys = (unsigned long long*)p; p += (size_t)NPAIR * 8;      // 256 KB
    int* nAmb = (int*)p;                          p += 256;
    int* hist = (int*)p;                          p += NOUT * 4;

    size_t zbytes = (size_t)NPAIR * 8 + 256 + NOUT * 4;
    hipMemsetAsync(keys, 0, zbytes, stream);

    convert_kernel<<<(NX4 + NW4) / 256, 256, 0, stream>>>(X, W, Xb, Wb);

    dim3 ggrid(NTOK / 128, NOUT / 128);  // 128 x 5
    gemm_bf16_kernel<<<ggrid, 256, 0, stream>>>(Xb, Wb, bias, logits,
                                                rec_m1, rec_m2, rec_id);

    reduce_kernel<<<NPAIR / 256, 256, 0, stream>>>(rec_m1, rec_m2, rec_id,
                                                   out_idx, list, nAmb);

    extract_kernel<<<NPAIR / 4, 256, 0, stream>>>(logits, list, nAmb, cand, cnt);

    rescore_kernel<<<NPAIR * MAXCAND / 256, 256, 0, stream>>>(
        X, W, bias, list, nAmb, cand, cnt, keys);

    gather_kernel<<<NTOK / 16, 256, 0, stream>>>(cb, keys, out, out_idx, hist);

    diversity_kernel<<<1, 256, 0, stream>>>(hist, out_loss);
}